// Round 1
// baseline (687.648 us; speedup 1.0000x reference)
//
#include <hip/hip_runtime.h>

// PhysicsConstrainedLoss: 6 loss terms over 6.4M edges / 200K nodes.
// Strategy: single fused edge pass -> 9 scalar partial sums + node scatter,
// then node reduce, then double-precision finalize.

constexpr int   kNodes      = 200000;
constexpr int   kEdges      = 6400000;
constexpr int   kEdgeBlocks = 2048;
constexpr int   kNodeBlocks = 256;
constexpr int   kNumSums    = 9;
constexpr float kEps        = 1e-6f;

__device__ __forceinline__ float softplusf(float t) {
    // log(1+exp(t)), numerically stable
    return fmaxf(t, 0.0f) + log1pf(expf(-fabsf(t)));
}

__global__ __launch_bounds__(256) void edge_pass(
    const float* __restrict__ nf,       // (N,4) node_features
    const float* __restrict__ logits,   // (E,)
    const float* __restrict__ eparams,  // (E,2)
    const float* __restrict__ labels,   // (E,)
    const float* __restrict__ tparams,  // (E,2)
    const int*   __restrict__ srcs,     // edge_index[0]
    const int*   __restrict__ dsts,     // edge_index[1]
    float*       __restrict__ node_cur, // (N,) zero-initialized
    float*       __restrict__ partials) // (kEdgeBlocks, kNumSums)
{
    float acc[kNumSums];
#pragma unroll
    for (int k = 0; k < kNumSums; ++k) acc[k] = 0.0f;

    const int stride = gridDim.x * blockDim.x;
    for (int e = blockIdx.x * blockDim.x + threadIdx.x; e < kEdges; e += stride) {
        float  x  = logits[e];
        float  y  = labels[e];
        float2 ep = *reinterpret_cast<const float2*>(eparams + 2 * e);
        float2 tp = *reinterpret_cast<const float2*>(tparams + 2 * e);
        int    s  = srcs[e];
        int    d  = dsts[e];
        float2 vs = *reinterpret_cast<const float2*>(nf + 4 * s);
        float2 vd = *reinterpret_cast<const float2*>(nf + 4 * d);

        float p   = 1.0f / (1.0f + expf(-x));
        float bce = y * softplusf(-x) + (1.0f - y) * softplusf(x);

        float dr  = ep.x - tp.x;
        float dx  = ep.y - tp.y;
        float par = dr * dr + dx * dx;

        float dvr = vs.x - vd.x;
        float dvi = vs.y - vd.y;
        float mag = sqrtf(dvr * dvr + dvi * dvi);

        float Rp   = ep.x + kEps;
        float den  = sqrtf(Rp * Rp + ep.y * ep.y);
        float curp = (mag / den) * p;
        float vdrop = mag * p;

        acc[0] += bce;
        acc[1] += par;
        acc[2] += p;
        acc[3] += p * ep.x;
        acc[4] += p * ep.y;
        acc[5] += p * ep.x * ep.x;
        acc[6] += p * ep.y * ep.y;
        acc[7] += vdrop;
        acc[8] += vdrop * vdrop;

        atomicAdd(node_cur + d,  curp);
        atomicAdd(node_cur + s, -curp);
    }

    // block reduction: wave shuffle then LDS across the 4 waves
    __shared__ float smem[4][kNumSums];
    const int lane = threadIdx.x & 63;
    const int wave = threadIdx.x >> 6;
#pragma unroll
    for (int k = 0; k < kNumSums; ++k) {
        float v = acc[k];
#pragma unroll
        for (int off = 32; off > 0; off >>= 1) v += __shfl_down(v, off, 64);
        if (lane == 0) smem[wave][k] = v;
    }
    __syncthreads();
    if (threadIdx.x < kNumSums) {
        float v = 0.0f;
#pragma unroll
        for (int w = 0; w < 4; ++w) v += smem[w][threadIdx.x];
        partials[blockIdx.x * kNumSums + threadIdx.x] = v;
    }
}

__global__ __launch_bounds__(256) void node_pass(
    const float* __restrict__ node_cur,
    float*       __restrict__ node_partials) // (kNodeBlocks,)
{
    float acc = 0.0f;
    const int stride = gridDim.x * blockDim.x;
    for (int i = blockIdx.x * blockDim.x + threadIdx.x; i < kNodes; i += stride) {
        float v = node_cur[i];
        acc += v * v;
    }
    __shared__ float smem[4];
    const int lane = threadIdx.x & 63;
    const int wave = threadIdx.x >> 6;
    float v = acc;
#pragma unroll
    for (int off = 32; off > 0; off >>= 1) v += __shfl_down(v, off, 64);
    if (lane == 0) smem[wave] = v;
    __syncthreads();
    if (threadIdx.x == 0) {
        node_partials[blockIdx.x] = smem[0] + smem[1] + smem[2] + smem[3];
    }
}

__global__ __launch_bounds__(64) void finalize(
    const float* __restrict__ partials,       // (kEdgeBlocks, kNumSums)
    const float* __restrict__ node_partials,  // (kNodeBlocks,)
    float*       __restrict__ out)            // (7,)
{
    const int lane = threadIdx.x;

    double sums[kNumSums];
#pragma unroll
    for (int k = 0; k < kNumSums; ++k) {
        double s = 0.0;
        for (int i = lane; i < kEdgeBlocks; i += 64)
            s += (double)partials[i * kNumSums + k];
#pragma unroll
        for (int off = 32; off > 0; off >>= 1) s += __shfl_down(s, off, 64);
        sums[k] = s;  // valid on lane 0
    }

    double nsum = 0.0;
    for (int i = lane; i < kNodeBlocks; i += 64)
        nsum += (double)node_partials[i];
#pragma unroll
    for (int off = 32; off > 0; off >>= 1) nsum += __shfl_down(nsum, off, 64);

    if (lane == 0) {
        const double E  = (double)kEdges;
        const double N  = (double)kNodes;
        const double s_bce = sums[0], s_par = sums[1], s_p = sums[2];
        const double s_pR = sums[3], s_pX = sums[4];
        const double s_pR2 = sums[5], s_pX2 = sums[6];
        const double s_v = sums[7], s_v2 = sums[8];

        double topology  = s_bce / E;
        double parameter = s_par / (2.0 * E);
        double kcl       = 0.1 * (nsum / N);

        double denom = s_p + (double)kEps;
        double mR = s_pR / denom;
        double mX = s_pX / denom;
        double varR = s_pR2 - 2.0 * mR * s_pR + mR * mR * s_p;
        double varX = s_pX2 - 2.0 * mX * s_pX + mX * mX * s_p;
        double param_consistency = 0.5 * (varR + varX);

        double voltage_consistency = (s_v2 - (s_v * s_v) / E) / (E - 1.0);
        double kvl = 0.1 * (param_consistency + voltage_consistency);

        double ecl = s_p - (N - 1.0);
        ecl = ecl * ecl;
        double radial   = 0.1 * (ecl + 0.1 * (s_p / E));
        double sparsity = 0.01 * (s_p / E);

        double total = topology + parameter + kcl + kvl + radial + sparsity;

        out[0] = (float)topology;
        out[1] = (float)parameter;
        out[2] = (float)kcl;
        out[3] = (float)kvl;
        out[4] = (float)radial;
        out[5] = (float)sparsity;
        out[6] = (float)total;
    }
}

extern "C" void kernel_launch(void* const* d_in, const int* in_sizes, int n_in,
                              void* d_out, int out_size, void* d_ws, size_t ws_size,
                              hipStream_t stream) {
    const float* nf      = (const float*)d_in[0];
    const float* logits  = (const float*)d_in[1];
    const float* eparams = (const float*)d_in[2];
    const float* labels  = (const float*)d_in[3];
    const float* tparams = (const float*)d_in[4];
    const int*   eidx    = (const int*)d_in[5];

    float* ws            = (float*)d_ws;
    float* node_cur      = ws;                              // kNodes floats
    float* partials      = ws + kNodes;                     // kEdgeBlocks*kNumSums
    float* node_partials = partials + kEdgeBlocks * kNumSums; // kNodeBlocks
    float* out           = (float*)d_out;

    hipMemsetAsync(node_cur, 0, kNodes * sizeof(float), stream);
    edge_pass<<<kEdgeBlocks, 256, 0, stream>>>(nf, logits, eparams, labels, tparams,
                                               eidx, eidx + kEdges, node_cur, partials);
    node_pass<<<kNodeBlocks, 256, 0, stream>>>(node_cur, node_partials);
    finalize<<<1, 64, 0, stream>>>(partials, node_partials, out);
}

// Round 2
// 682.730 us; speedup vs baseline: 1.0072x; 1.0072x over previous
//
#include <hip/hip_runtime.h>

// PhysicsConstrainedLoss: 6 loss terms over 6.4M edges / 200K nodes.
// R1: per-XCD privatized node_cur replicas + workgroup-scope atomics so the
// scatter is performed in the XCD-local L2 instead of the memory-side
// coherence point (device-scope fp32 atomics were 400 MB of HBM writes).

constexpr int   kNodes      = 200000;
constexpr int   kEdges      = 6400000;
constexpr int   kEdgeBlocks = 2048;
constexpr int   kNodeBlocks = 256;
constexpr int   kNumSums    = 9;
constexpr int   kXcds       = 8;
constexpr float kEps        = 1e-6f;

__device__ __forceinline__ float softplusf(float t) {
    return fmaxf(t, 0.0f) + log1pf(expf(-fabsf(t)));
}

__device__ __forceinline__ unsigned xcc_id() {
    unsigned x;
    // HW_REG_XCC_ID = 20 on gfx940+/gfx950 (measured: returns 0..7 on MI355X)
    asm volatile("s_getreg_b32 %0, hwreg(20, 0, 32)" : "=s"(x));
    return x & 7u;
}

template <bool PER_XCD>
__global__ __launch_bounds__(256) void edge_pass(
    const float* __restrict__ nf,       // (N,4) node_features
    const float* __restrict__ logits,   // (E,)
    const float* __restrict__ eparams,  // (E,2)
    const float* __restrict__ labels,   // (E,)
    const float* __restrict__ tparams,  // (E,2)
    const int*   __restrict__ srcs,     // edge_index[0]
    const int*   __restrict__ dsts,     // edge_index[1]
    float*       __restrict__ node_cur, // (R, N) zero-initialized replicas
    float*       __restrict__ partials) // (kEdgeBlocks, kNumSums)
{
    float* nc = node_cur;
    if (PER_XCD) nc += (size_t)xcc_id() * kNodes;

    float acc[kNumSums];
#pragma unroll
    for (int k = 0; k < kNumSums; ++k) acc[k] = 0.0f;

    const int stride = gridDim.x * blockDim.x;
    for (int e = blockIdx.x * blockDim.x + threadIdx.x; e < kEdges; e += stride) {
        float  x  = logits[e];
        float  y  = labels[e];
        float2 ep = *reinterpret_cast<const float2*>(eparams + 2 * e);
        float2 tp = *reinterpret_cast<const float2*>(tparams + 2 * e);
        int    s  = srcs[e];
        int    d  = dsts[e];
        float2 vs = *reinterpret_cast<const float2*>(nf + 4 * s);
        float2 vd = *reinterpret_cast<const float2*>(nf + 4 * d);

        float p   = 1.0f / (1.0f + expf(-x));
        float bce = y * softplusf(-x) + (1.0f - y) * softplusf(x);

        float dr  = ep.x - tp.x;
        float dx  = ep.y - tp.y;
        float par = dr * dr + dx * dx;

        float dvr = vs.x - vd.x;
        float dvi = vs.y - vd.y;
        float mag = sqrtf(dvr * dvr + dvi * dvi);

        float Rp   = ep.x + kEps;
        float den  = sqrtf(Rp * Rp + ep.y * ep.y);
        float curp = (mag / den) * p;
        float vdrop = mag * p;

        acc[0] += bce;
        acc[1] += par;
        acc[2] += p;
        acc[3] += p * ep.x;
        acc[4] += p * ep.y;
        acc[5] += p * ep.x * ep.x;
        acc[6] += p * ep.y * ep.y;
        acc[7] += vdrop;
        acc[8] += vdrop * vdrop;

        if (PER_XCD) {
            // Performed in the XCD-local TCC (no sc1): replica is private to
            // this XCD, and L2 is the atomic point for every CU on it.
            __hip_atomic_fetch_add(nc + d,  curp, __ATOMIC_RELAXED,
                                   __HIP_MEMORY_SCOPE_WORKGROUP);
            __hip_atomic_fetch_add(nc + s, -curp, __ATOMIC_RELAXED,
                                   __HIP_MEMORY_SCOPE_WORKGROUP);
        } else {
            atomicAdd(nc + d,  curp);
            atomicAdd(nc + s, -curp);
        }
    }

    __shared__ float smem[4][kNumSums];
    const int lane = threadIdx.x & 63;
    const int wave = threadIdx.x >> 6;
#pragma unroll
    for (int k = 0; k < kNumSums; ++k) {
        float v = acc[k];
#pragma unroll
        for (int off = 32; off > 0; off >>= 1) v += __shfl_down(v, off, 64);
        if (lane == 0) smem[wave][k] = v;
    }
    __syncthreads();
    if (threadIdx.x < kNumSums) {
        float v = 0.0f;
#pragma unroll
        for (int w = 0; w < 4; ++w) v += smem[w][threadIdx.x];
        partials[blockIdx.x * kNumSums + threadIdx.x] = v;
    }
}

__global__ __launch_bounds__(256) void node_pass(
    const float* __restrict__ node_cur,       // (R, N)
    float*       __restrict__ node_partials,  // (kNodeBlocks,)
    int replicas)
{
    float acc = 0.0f;
    const int stride = gridDim.x * blockDim.x;
    for (int i = blockIdx.x * blockDim.x + threadIdx.x; i < kNodes; i += stride) {
        float v = 0.0f;
        for (int r = 0; r < replicas; ++r) v += node_cur[(size_t)r * kNodes + i];
        acc += v * v;
    }
    __shared__ float smem[4];
    const int lane = threadIdx.x & 63;
    const int wave = threadIdx.x >> 6;
    float v = acc;
#pragma unroll
    for (int off = 32; off > 0; off >>= 1) v += __shfl_down(v, off, 64);
    if (lane == 0) smem[wave] = v;
    __syncthreads();
    if (threadIdx.x == 0) {
        node_partials[blockIdx.x] = smem[0] + smem[1] + smem[2] + smem[3];
    }
}

__global__ __launch_bounds__(64) void finalize(
    const float* __restrict__ partials,       // (kEdgeBlocks, kNumSums)
    const float* __restrict__ node_partials,  // (kNodeBlocks,)
    float*       __restrict__ out)            // (7,)
{
    const int lane = threadIdx.x;

    double sums[kNumSums];
#pragma unroll
    for (int k = 0; k < kNumSums; ++k) {
        double s = 0.0;
        for (int i = lane; i < kEdgeBlocks; i += 64)
            s += (double)partials[i * kNumSums + k];
#pragma unroll
        for (int off = 32; off > 0; off >>= 1) s += __shfl_down(s, off, 64);
        sums[k] = s;  // valid on lane 0
    }

    double nsum = 0.0;
    for (int i = lane; i < kNodeBlocks; i += 64)
        nsum += (double)node_partials[i];
#pragma unroll
    for (int off = 32; off > 0; off >>= 1) nsum += __shfl_down(nsum, off, 64);

    if (lane == 0) {
        const double E  = (double)kEdges;
        const double N  = (double)kNodes;
        const double s_bce = sums[0], s_par = sums[1], s_p = sums[2];
        const double s_pR = sums[3], s_pX = sums[4];
        const double s_pR2 = sums[5], s_pX2 = sums[6];
        const double s_v = sums[7], s_v2 = sums[8];

        double topology  = s_bce / E;
        double parameter = s_par / (2.0 * E);
        double kcl       = 0.1 * (nsum / N);

        double denom = s_p + (double)kEps;
        double mR = s_pR / denom;
        double mX = s_pX / denom;
        double varR = s_pR2 - 2.0 * mR * s_pR + mR * mR * s_p;
        double varX = s_pX2 - 2.0 * mX * s_pX + mX * mX * s_p;
        double param_consistency = 0.5 * (varR + varX);

        double voltage_consistency = (s_v2 - (s_v * s_v) / E) / (E - 1.0);
        double kvl = 0.1 * (param_consistency + voltage_consistency);

        double ecl = s_p - (N - 1.0);
        ecl = ecl * ecl;
        double radial   = 0.1 * (ecl + 0.1 * (s_p / E));
        double sparsity = 0.01 * (s_p / E);

        double total = topology + parameter + kcl + kvl + radial + sparsity;

        out[0] = (float)topology;
        out[1] = (float)parameter;
        out[2] = (float)kcl;
        out[3] = (float)kvl;
        out[4] = (float)radial;
        out[5] = (float)sparsity;
        out[6] = (float)total;
    }
}

extern "C" void kernel_launch(void* const* d_in, const int* in_sizes, int n_in,
                              void* d_out, int out_size, void* d_ws, size_t ws_size,
                              hipStream_t stream) {
    const float* nf      = (const float*)d_in[0];
    const float* logits  = (const float*)d_in[1];
    const float* eparams = (const float*)d_in[2];
    const float* labels  = (const float*)d_in[3];
    const float* tparams = (const float*)d_in[4];
    const int*   eidx    = (const int*)d_in[5];

    // Workspace layout: [replicas*kNodes node_cur][2048*9 partials][256 node_partials]
    const size_t tail = (size_t)(kEdgeBlocks * kNumSums + kNodeBlocks) * sizeof(float);
    const bool per_xcd = ws_size >= (size_t)kXcds * kNodes * sizeof(float) + tail;
    const int replicas = per_xcd ? kXcds : 1;

    float* ws            = (float*)d_ws;
    float* node_cur      = ws;
    float* partials      = ws + (size_t)replicas * kNodes;
    float* node_partials = partials + kEdgeBlocks * kNumSums;
    float* out           = (float*)d_out;

    hipMemsetAsync(node_cur, 0, (size_t)replicas * kNodes * sizeof(float), stream);
    if (per_xcd) {
        edge_pass<true><<<kEdgeBlocks, 256, 0, stream>>>(
            nf, logits, eparams, labels, tparams,
            eidx, eidx + kEdges, node_cur, partials);
    } else {
        edge_pass<false><<<kEdgeBlocks, 256, 0, stream>>>(
            nf, logits, eparams, labels, tparams,
            eidx, eidx + kEdges, node_cur, partials);
    }
    node_pass<<<kNodeBlocks, 256, 0, stream>>>(node_cur, node_partials, replicas);
    finalize<<<1, 64, 0, stream>>>(partials, node_partials, out);
}

// Round 3
// 239.659 us; speedup vs baseline: 2.8693x; 2.8488x over previous
//
#include <hip/hip_runtime.h>

// PhysicsConstrainedLoss: 6 loss terms over 6.4M edges / 200K nodes.
// R2: global fp32 atomic scatter (12.8M atomics -> memory-side coherence
// point, 20G/s hard limit, 400MB of 32B EA writes) replaced by two-level
// binning: per-block LDS histogram + one range-reservation atomic per
// (block,bucket), packed int20-quantized contributions, then per-bucket LDS
// integer accumulation. Integer sums are order-independent -> deterministic.

constexpr int   kNodes        = 200000;
constexpr int   kEdges        = 6400000;
constexpr int   kNumSums      = 9;
constexpr float kEps          = 1e-6f;

constexpr int   kBucketShift  = 12;                  // 4096 nodes / bucket
constexpr int   kBucketSize   = 1 << kBucketShift;
constexpr int   kBuckets      = (kNodes + kBucketSize - 1) / kBucketSize;  // 49
constexpr int   kCap          = 272 * 1024;          // per-bucket capacity (E[..]=262144, +~20 sigma)
constexpr int   kEdgesPerBlk  = 4096;
constexpr int   kP1Blocks     = (kEdges + kEdgesPerBlk - 1) / kEdgesPerBlk; // 1563
constexpr int   kMSlices      = 16;
constexpr int   kP2Blocks     = kBuckets * kMSlices; // 784
constexpr int   kNodeBlocks   = 256;
constexpr int   kFbBlocks     = 2048;                // fallback grid
constexpr float kQScale       = 65536.0f;
constexpr float kQInv         = 1.0f / 65536.0f;
constexpr int   kQBias        = 524288;              // int20 bias

__device__ __forceinline__ float softplusf(float t) {
    return fmaxf(t, 0.0f) + log1pf(expf(-fabsf(t)));
}

// ---------------------------------------------------------------- phase 1
__global__ __launch_bounds__(256) void p1_edges(
    const float* __restrict__ nf,
    const float* __restrict__ logits,
    const float* __restrict__ eparams,
    const float* __restrict__ labels,
    const float* __restrict__ tparams,
    const int*   __restrict__ srcs,
    const int*   __restrict__ dsts,
    unsigned*    __restrict__ pairs,    // (kBuckets, kCap) packed entries
    int*         __restrict__ gcount,   // (kBuckets,) zero-initialized
    float*       __restrict__ partials) // (kP1Blocks, kNumSums)
{
    __shared__ int   q_lds[kEdgesPerBlk];
    __shared__ int   hist[kBuckets];
    __shared__ int   base[kBuckets];
    __shared__ int   cursor[kBuckets];
    __shared__ float smem[4][kNumSums];

    const int tid = threadIdx.x;
    for (int b = tid; b < kBuckets; b += 256) { hist[b] = 0; cursor[b] = 0; }
    __syncthreads();

    float acc[kNumSums];
#pragma unroll
    for (int k = 0; k < kNumSums; ++k) acc[k] = 0.0f;

    const int e0 = blockIdx.x * kEdgesPerBlk;

    // ---- sub-pass 1: full compute, stash quantized curp, bucket histogram
#pragma unroll 1
    for (int i = 0; i < kEdgesPerBlk / 256; ++i) {
        const int e = e0 + i * 256 + tid;
        int q = 0;
        if (e < kEdges) {
            float  x  = logits[e];
            float  y  = labels[e];
            float2 ep = *reinterpret_cast<const float2*>(eparams + 2 * e);
            float2 tp = *reinterpret_cast<const float2*>(tparams + 2 * e);
            int    s  = srcs[e];
            int    d  = dsts[e];
            float2 vs = *reinterpret_cast<const float2*>(nf + 4 * s);
            float2 vd = *reinterpret_cast<const float2*>(nf + 4 * d);

            float p   = 1.0f / (1.0f + expf(-x));
            float bce = y * softplusf(-x) + (1.0f - y) * softplusf(x);

            float dr  = ep.x - tp.x;
            float dx  = ep.y - tp.y;
            float par = dr * dr + dx * dx;

            float dvr = vs.x - vd.x;
            float dvi = vs.y - vd.y;
            float mag = sqrtf(dvr * dvr + dvi * dvi);

            float Rp    = ep.x + kEps;
            float den   = sqrtf(Rp * Rp + ep.y * ep.y);
            float curp  = (mag / den) * p;
            float vdrop = mag * p;

            acc[0] += bce;
            acc[1] += par;
            acc[2] += p;
            acc[3] += p * ep.x;
            acc[4] += p * ep.y;
            acc[5] += p * ep.x * ep.x;
            acc[6] += p * ep.y * ep.y;
            acc[7] += vdrop;
            acc[8] += vdrop * vdrop;

            q = __float2int_rn(curp * kQScale);
            q = max(-(kQBias - 1), min(kQBias - 1, q));

            atomicAdd(&hist[d >> kBucketShift], 1);
            atomicAdd(&hist[s >> kBucketShift], 1);
        }
        q_lds[i * 256 + tid] = q;
    }
    __syncthreads();

    // ---- reserve contiguous global ranges: ONE atomic per (block,bucket)
    for (int b = tid; b < kBuckets; b += 256)
        base[b] = atomicAdd(&gcount[b], hist[b]);
    __syncthreads();

    // ---- sub-pass 2: re-read indices (L1/L2-hot), emit packed entries
#pragma unroll 1
    for (int i = 0; i < kEdgesPerBlk / 256; ++i) {
        const int e = e0 + i * 256 + tid;
        if (e < kEdges) {
            const int s = srcs[e];
            const int d = dsts[e];
            const int q = q_lds[i * 256 + tid];
            {
                const int b    = d >> kBucketShift;
                const int slot = base[b] + atomicAdd(&cursor[b], 1);
                if (slot < kCap)
                    pairs[(size_t)b * kCap + slot] =
                        ((unsigned)(d & (kBucketSize - 1)) << 20) | (unsigned)(q + kQBias);
            }
            {
                const int b    = s >> kBucketShift;
                const int slot = base[b] + atomicAdd(&cursor[b], 1);
                if (slot < kCap)
                    pairs[(size_t)b * kCap + slot] =
                        ((unsigned)(s & (kBucketSize - 1)) << 20) | (unsigned)(-q + kQBias);
            }
        }
    }

    // ---- block reduction of the 9 scalar sums
    const int lane = tid & 63;
    const int wave = tid >> 6;
#pragma unroll
    for (int k = 0; k < kNumSums; ++k) {
        float v = acc[k];
#pragma unroll
        for (int off = 32; off > 0; off >>= 1) v += __shfl_down(v, off, 64);
        if (lane == 0) smem[wave][k] = v;
    }
    __syncthreads();
    if (tid < kNumSums) {
        float v = 0.0f;
#pragma unroll
        for (int w = 0; w < 4; ++w) v += smem[w][tid];
        partials[blockIdx.x * kNumSums + tid] = v;
    }
}

// ---------------------------------------------------------------- phase 2
__global__ __launch_bounds__(256) void p2_buckets(
    const unsigned* __restrict__ pairs,
    const int*      __restrict__ gcount,
    int*            __restrict__ out_i32)  // (kP2Blocks, kBucketSize)
{
    __shared__ int accs[kBucketSize];
    const int b = blockIdx.x / kMSlices;
    const int m = blockIdx.x % kMSlices;

    for (int i = threadIdx.x; i < kBucketSize; i += 256) accs[i] = 0;
    __syncthreads();

    const int count = min(gcount[b], kCap);
    const int s0 = (int)((long long)count * m / kMSlices);
    const int s1 = (int)((long long)count * (m + 1) / kMSlices);
    const unsigned* pb = pairs + (size_t)b * kCap;

    for (int i = s0 + threadIdx.x; i < s1; i += 256) {
        const unsigned u = pb[i];
        atomicAdd(&accs[u >> 20], (int)(u & 0xFFFFFu) - kQBias);
    }
    __syncthreads();

    int* o = out_i32 + (size_t)blockIdx.x * kBucketSize;
    for (int i = threadIdx.x; i < kBucketSize; i += 256) o[i] = accs[i];
}

// ---------------------------------------------------------------- node pass
__global__ __launch_bounds__(256) void node_pass_binned(
    const int* __restrict__ out_i32,
    float*     __restrict__ node_partials)
{
    float acc = 0.0f;
    const int stride = gridDim.x * blockDim.x;
    for (int n = blockIdx.x * blockDim.x + threadIdx.x; n < kNodes; n += stride) {
        const int b = n >> kBucketShift;
        const int s = n & (kBucketSize - 1);
        const int* p = out_i32 + ((size_t)b * kMSlices) * kBucketSize + s;
        int v = 0;
#pragma unroll
        for (int m = 0; m < kMSlices; ++m) v += p[(size_t)m * kBucketSize];
        const float nc = (float)v * kQInv;
        acc += nc * nc;
    }
    __shared__ float smem[4];
    const int lane = threadIdx.x & 63;
    const int wave = threadIdx.x >> 6;
    float v = acc;
#pragma unroll
    for (int off = 32; off > 0; off >>= 1) v += __shfl_down(v, off, 64);
    if (lane == 0) smem[wave] = v;
    __syncthreads();
    if (threadIdx.x == 0)
        node_partials[blockIdx.x] = smem[0] + smem[1] + smem[2] + smem[3];
}

// ---------------------------------------------------------------- fallback (R1 path)
__global__ __launch_bounds__(256) void edge_pass_atomic(
    const float* __restrict__ nf, const float* __restrict__ logits,
    const float* __restrict__ eparams, const float* __restrict__ labels,
    const float* __restrict__ tparams, const int* __restrict__ srcs,
    const int* __restrict__ dsts, float* __restrict__ node_cur,
    float* __restrict__ partials)
{
    float acc[kNumSums];
#pragma unroll
    for (int k = 0; k < kNumSums; ++k) acc[k] = 0.0f;
    const int stride = gridDim.x * blockDim.x;
    for (int e = blockIdx.x * blockDim.x + threadIdx.x; e < kEdges; e += stride) {
        float  x  = logits[e];
        float  y  = labels[e];
        float2 ep = *reinterpret_cast<const float2*>(eparams + 2 * e);
        float2 tp = *reinterpret_cast<const float2*>(tparams + 2 * e);
        int    s  = srcs[e];
        int    d  = dsts[e];
        float2 vs = *reinterpret_cast<const float2*>(nf + 4 * s);
        float2 vd = *reinterpret_cast<const float2*>(nf + 4 * d);
        float p   = 1.0f / (1.0f + expf(-x));
        float bce = y * softplusf(-x) + (1.0f - y) * softplusf(x);
        float dr = ep.x - tp.x, dx = ep.y - tp.y;
        float dvr = vs.x - vd.x, dvi = vs.y - vd.y;
        float mag = sqrtf(dvr * dvr + dvi * dvi);
        float Rp  = ep.x + kEps;
        float den = sqrtf(Rp * Rp + ep.y * ep.y);
        float curp = (mag / den) * p;
        float vdrop = mag * p;
        acc[0] += bce; acc[1] += dr * dr + dx * dx; acc[2] += p;
        acc[3] += p * ep.x; acc[4] += p * ep.y;
        acc[5] += p * ep.x * ep.x; acc[6] += p * ep.y * ep.y;
        acc[7] += vdrop; acc[8] += vdrop * vdrop;
        atomicAdd(node_cur + d,  curp);
        atomicAdd(node_cur + s, -curp);
    }
    __shared__ float smem[4][kNumSums];
    const int lane = threadIdx.x & 63, wave = threadIdx.x >> 6;
#pragma unroll
    for (int k = 0; k < kNumSums; ++k) {
        float v = acc[k];
#pragma unroll
        for (int off = 32; off > 0; off >>= 1) v += __shfl_down(v, off, 64);
        if (lane == 0) smem[wave][k] = v;
    }
    __syncthreads();
    if (threadIdx.x < kNumSums) {
        float v = 0.0f;
#pragma unroll
        for (int w = 0; w < 4; ++w) v += smem[w][threadIdx.x];
        partials[blockIdx.x * kNumSums + threadIdx.x] = v;
    }
}

__global__ __launch_bounds__(256) void node_pass_flat(
    const float* __restrict__ node_cur, float* __restrict__ node_partials)
{
    float acc = 0.0f;
    const int stride = gridDim.x * blockDim.x;
    for (int i = blockIdx.x * blockDim.x + threadIdx.x; i < kNodes; i += stride) {
        float v = node_cur[i];
        acc += v * v;
    }
    __shared__ float smem[4];
    const int lane = threadIdx.x & 63, wave = threadIdx.x >> 6;
    float v = acc;
#pragma unroll
    for (int off = 32; off > 0; off >>= 1) v += __shfl_down(v, off, 64);
    if (lane == 0) smem[wave] = v;
    __syncthreads();
    if (threadIdx.x == 0)
        node_partials[blockIdx.x] = smem[0] + smem[1] + smem[2] + smem[3];
}

// ---------------------------------------------------------------- finalize
__global__ __launch_bounds__(64) void finalize(
    const float* __restrict__ partials, int nblocks,
    const float* __restrict__ node_partials,
    float*       __restrict__ out)
{
    const int lane = threadIdx.x;
    double sums[kNumSums];
#pragma unroll
    for (int k = 0; k < kNumSums; ++k) {
        double s = 0.0;
        for (int i = lane; i < nblocks; i += 64)
            s += (double)partials[i * kNumSums + k];
#pragma unroll
        for (int off = 32; off > 0; off >>= 1) s += __shfl_down(s, off, 64);
        sums[k] = s;
    }
    double nsum = 0.0;
    for (int i = lane; i < kNodeBlocks; i += 64)
        nsum += (double)node_partials[i];
#pragma unroll
    for (int off = 32; off > 0; off >>= 1) nsum += __shfl_down(nsum, off, 64);

    if (lane == 0) {
        const double E = (double)kEdges, N = (double)kNodes;
        const double s_bce = sums[0], s_par = sums[1], s_p = sums[2];
        const double s_pR = sums[3], s_pX = sums[4];
        const double s_pR2 = sums[5], s_pX2 = sums[6];
        const double s_v = sums[7], s_v2 = sums[8];

        double topology  = s_bce / E;
        double parameter = s_par / (2.0 * E);
        double kcl       = 0.1 * (nsum / N);

        double denom = s_p + (double)kEps;
        double mR = s_pR / denom, mX = s_pX / denom;
        double varR = s_pR2 - 2.0 * mR * s_pR + mR * mR * s_p;
        double varX = s_pX2 - 2.0 * mX * s_pX + mX * mX * s_p;
        double param_consistency = 0.5 * (varR + varX);
        double voltage_consistency = (s_v2 - (s_v * s_v) / E) / (E - 1.0);
        double kvl = 0.1 * (param_consistency + voltage_consistency);

        double ecl = s_p - (N - 1.0);
        ecl = ecl * ecl;
        double radial   = 0.1 * (ecl + 0.1 * (s_p / E));
        double sparsity = 0.01 * (s_p / E);
        double total = topology + parameter + kcl + kvl + radial + sparsity;

        out[0] = (float)topology;  out[1] = (float)parameter;
        out[2] = (float)kcl;       out[3] = (float)kvl;
        out[4] = (float)radial;    out[5] = (float)sparsity;
        out[6] = (float)total;
    }
}

extern "C" void kernel_launch(void* const* d_in, const int* in_sizes, int n_in,
                              void* d_out, int out_size, void* d_ws, size_t ws_size,
                              hipStream_t stream) {
    const float* nf      = (const float*)d_in[0];
    const float* logits  = (const float*)d_in[1];
    const float* eparams = (const float*)d_in[2];
    const float* labels  = (const float*)d_in[3];
    const float* tparams = (const float*)d_in[4];
    const int*   eidx    = (const int*)d_in[5];
    float* out           = (float*)d_out;

    // binned layout: [pairs][out_i32][gcount(pad 64)][partials][node_partials]
    const size_t n_pairs  = (size_t)kBuckets * kCap;
    const size_t n_outi32 = (size_t)kP2Blocks * kBucketSize;
    const size_t n_words  = n_pairs + n_outi32 + 64 +
                            (size_t)kP1Blocks * kNumSums + kNodeBlocks;

    if (ws_size >= n_words * sizeof(unsigned)) {
        unsigned* pairs        = (unsigned*)d_ws;
        int*      out_i32      = (int*)(pairs + n_pairs);
        int*      gcount       = (int*)(out_i32 + n_outi32);
        float*    partials     = (float*)(gcount + 64);
        float*    node_partials= partials + (size_t)kP1Blocks * kNumSums;

        hipMemsetAsync(gcount, 0, kBuckets * sizeof(int), stream);
        p1_edges<<<kP1Blocks, 256, 0, stream>>>(nf, logits, eparams, labels, tparams,
                                                eidx, eidx + kEdges,
                                                pairs, gcount, partials);
        p2_buckets<<<kP2Blocks, 256, 0, stream>>>(pairs, gcount, out_i32);
        node_pass_binned<<<kNodeBlocks, 256, 0, stream>>>(out_i32, node_partials);
        finalize<<<1, 64, 0, stream>>>(partials, kP1Blocks, node_partials, out);
    } else {
        // fallback: R1 atomic path
        float* node_cur      = (float*)d_ws;
        float* partials      = node_cur + kNodes;
        float* node_partials = partials + (size_t)kFbBlocks * kNumSums;

        hipMemsetAsync(node_cur, 0, kNodes * sizeof(float), stream);
        edge_pass_atomic<<<kFbBlocks, 256, 0, stream>>>(nf, logits, eparams, labels,
                                                        tparams, eidx, eidx + kEdges,
                                                        node_cur, partials);
        node_pass_flat<<<kNodeBlocks, 256, 0, stream>>>(node_cur, node_partials);
        finalize<<<1, 64, 0, stream>>>(partials, kFbBlocks, node_partials, out);
    }
}